// Round 1
// baseline (99.150 us; speedup 1.0000x reference)
//
#include <hip/hip_runtime.h>
#include <math.h>

#define N_INW     1024
#define N_DEPTH   8
#define N_GROW    512
#define N_BATCH   4096
#define N_THREADS 128    // 2 independent waves/WG; wave cp owns its own slab
#define N_LAYERS  64
#define SLAB_B    19584  // (4608 + 288 pad) * 4 B per wave

typedef __attribute__((ext_vector_type(2))) float    F2;
typedef __attribute__((ext_vector_type(2))) _Float16 h2;

// ---- setup: fp16 cs table + precomputed LDS byte-offsets ----
// layer g, lane blk: 8 cos halves at byte g*2048 + blk*32, 8 sin halves at +16.
__global__ void precompute_kernel(const float* __restrict__ angles,
                                  const int*   __restrict__ indices,
                                  _Float16* __restrict__ csh,
                                  int*   __restrict__ addrs) {
    int i = blockIdx.x * blockDim.x + threadIdx.x;
    if (i < N_LAYERS * 512) {
        int g = i >> 9, p = i & 511, blk = p >> 3, j = p & 7;
        float a = angles[i];
        _Float16* base = csh + g * 1024 + blk * 16;   // halves
        base[j]     = (_Float16)cosf(a);
        base[8 + j] = (_Float16)sinf(a);
    }
    if (i < N_DEPTH * N_INW) {
        int v = indices[i];
        addrs[i] = (v + (v >> 4)) << 2;
    }
}

// fp16 slab (per wave): row r -> half2 at byte (r + (r>>4))<<2.
#define ADDR(r) ((((r) + ((r) >> 4))) << 2)

#define LDH(A)    __builtin_bit_cast(h2, *(const unsigned*)(L + (A)))
#define STH(A, V) do { *(unsigned*)(L + (A)) =                                 \
                       __builtin_bit_cast(unsigned, (V)); } while (0)

#define PKU(x, y) __builtin_bit_cast(unsigned int,                             \
                      __builtin_amdgcn_cvt_pkrtz((x), (y)))

// ---- hand-scheduled VOP3P 2x2 rotation ----
// cs words hold (pair_j0, pair_j1) in (lo, hi) halves. ROTP_L consumes the LOW
// half of C/S broadcast to both batch lanes via op_sel (no splat instructions);
// ROTP_H consumes the HIGH half. The c*h - s*l negation folds into neg_lo/
// neg_hi on the fma's src2. Exactly 4 VOP3P per rotation pair.
#define ROTP_L(LOv, HIv, CU, SU) do {                                          \
    unsigned _t0, _t1;                                                         \
    asm("v_pk_mul_f16 %2, %5, %1 op_sel:[0,0] op_sel_hi:[0,1]\n\t"             \
        "v_pk_mul_f16 %3, %5, %0 op_sel:[0,0] op_sel_hi:[0,1]\n\t"             \
        "v_pk_fma_f16 %0, %4, %0, %2 op_sel:[0,0,0] op_sel_hi:[0,1,1]\n\t"     \
        "v_pk_fma_f16 %1, %4, %1, %3 op_sel:[0,0,0] op_sel_hi:[0,1,1] "        \
            "neg_lo:[0,0,1] neg_hi:[0,0,1]"                                    \
        : "+v"(LOv), "+v"(HIv), "=&v"(_t0), "=&v"(_t1)                         \
        : "v"(CU), "v"(SU));                                                   \
  } while (0)

#define ROTP_H(LOv, HIv, CU, SU) do {                                          \
    unsigned _t0, _t1;                                                         \
    asm("v_pk_mul_f16 %2, %5, %1 op_sel:[1,0] op_sel_hi:[1,1]\n\t"             \
        "v_pk_mul_f16 %3, %5, %0 op_sel:[1,0] op_sel_hi:[1,1]\n\t"             \
        "v_pk_fma_f16 %0, %4, %0, %2 op_sel:[1,0,0] op_sel_hi:[1,1,1]\n\t"     \
        "v_pk_fma_f16 %1, %4, %1, %3 op_sel:[1,0,0] op_sel_hi:[1,1,1] "        \
            "neg_lo:[0,0,1] neg_hi:[0,0,1]"                                    \
        : "+v"(LOv), "+v"(HIv), "=&v"(_t0), "=&v"(_t1)                         \
        : "v"(CU), "v"(SU));                                                   \
  } while (0)

// ---- per-set register state (A / B ping-pong, full-module prefetch) ----
#define DECL_SET(P)                                                            \
    uint4 P##c0, P##s0, P##c1, P##s1, P##c2, P##s2, P##c3, P##s3,              \
          P##c4, P##s4, P##c5, P##s5, P##c6, P##s6, P##c7, P##s7;              \
    int4  P##i0, P##i1, P##i2, P##i3;                                          \
    float4 P##bA, P##bB;

// synthesize one packed layer from angles (fallback path)
#define SYN1(P, K, ANB) do {                                                   \
    const float4* _p = (const float4*)((ANB) + (K)*512 + (blk << 3));          \
    float4 _u = _p[0], _v = _p[1];                                             \
    float _c0,_c1,_c2,_c3,_c4,_c5,_c6,_c7,_t0,_t1,_t2,_t3,_t4,_t5,_t6,_t7;     \
    __sincosf(_u.x,&_t0,&_c0); __sincosf(_u.y,&_t1,&_c1);                      \
    __sincosf(_u.z,&_t2,&_c2); __sincosf(_u.w,&_t3,&_c3);                      \
    __sincosf(_v.x,&_t4,&_c4); __sincosf(_v.y,&_t5,&_c5);                      \
    __sincosf(_v.z,&_t6,&_c6); __sincosf(_v.w,&_t7,&_c7);                      \
    P##c##K = make_uint4(PKU(_c0,_c1),PKU(_c2,_c3),PKU(_c4,_c5),PKU(_c6,_c7)); \
    P##s##K = make_uint4(PKU(_t0,_t1),PKU(_t2,_t3),PKU(_t4,_t5),PKU(_t6,_t7)); \
  } while (0)

#define LOADCS1(P, K, CSN, ANB) do { if (USE_TABLE) {                          \
    const char* _b = (CSN) + (blk << 5) + (K)*2048;                            \
    P##c##K = *(const uint4*)(_b); P##s##K = *(const uint4*)(_b + 16);         \
  } else { SYN1(P, K, ANB); } } while (0)

#define LOADCS8(P, CSN, ANB) do {                                              \
    LOADCS1(P,0,CSN,ANB); LOADCS1(P,1,CSN,ANB); LOADCS1(P,2,CSN,ANB);          \
    LOADCS1(P,3,CSN,ANB); LOADCS1(P,4,CSN,ANB); LOADCS1(P,5,CSN,ANB);          \
    LOADCS1(P,6,CSN,ANB); LOADCS1(P,7,CSN,ANB); } while (0)
#define LOADCS4(P, CSN, ANB) do {                                              \
    LOADCS1(P,0,CSN,ANB); LOADCS1(P,1,CSN,ANB); LOADCS1(P,2,CSN,ANB);          \
    LOADCS1(P,3,CSN,ANB); } while (0)

#define TR(v) (((v) + ((v) >> 4)) << 2)
#define LOAD_AB(P, ATN, INB, BIN) do { if (USE_TABLE) {                        \
    const int4* _ip = (const int4*)((ATN) + (blk << 4));                       \
    P##i0=_ip[0]; P##i1=_ip[1]; P##i2=_ip[2]; P##i3=_ip[3];                    \
  } else {                                                                     \
    const int4* _ip = (const int4*)((INB) + (blk << 4));                       \
    int4 _v0=_ip[0], _v1=_ip[1], _v2=_ip[2], _v3=_ip[3];                       \
    P##i0.x=TR(_v0.x); P##i0.y=TR(_v0.y); P##i0.z=TR(_v0.z); P##i0.w=TR(_v0.w);\
    P##i1.x=TR(_v1.x); P##i1.y=TR(_v1.y); P##i1.z=TR(_v1.z); P##i1.w=TR(_v1.w);\
    P##i2.x=TR(_v2.x); P##i2.y=TR(_v2.y); P##i2.z=TR(_v2.z); P##i2.w=TR(_v2.w);\
    P##i3.x=TR(_v3.x); P##i3.y=TR(_v3.y); P##i3.z=TR(_v3.z); P##i3.w=TR(_v3.w);\
  }                                                                            \
  const float4* _bp = (const float4*)((BIN) + (blk << 3));                     \
  P##bA = _bp[0]; P##bB = _bp[1]; } while (0)

// rotation layers consuming PACKED cs (value j: j0=lo(x),j1=hi(x),...,j7=hi(w))
#define HROTS1(C,S) do {                                                       \
    ROTP_L(x0,x1,  C.x,S.x); ROTP_H(x2,x3,  C.x,S.x);                          \
    ROTP_L(x4,x5,  C.y,S.y); ROTP_H(x6,x7,  C.y,S.y);                          \
    ROTP_L(x8,x9,  C.z,S.z); ROTP_H(x10,x11,C.z,S.z);                          \
    ROTP_L(x12,x13,C.w,S.w); ROTP_H(x14,x15,C.w,S.w);                          \
  } while (0)
#define HROTS2(C,S) do {                                                       \
    ROTP_L(x0,x2,  C.x,S.x); ROTP_H(x1,x3,  C.x,S.x);                          \
    ROTP_L(x4,x6,  C.y,S.y); ROTP_H(x5,x7,  C.y,S.y);                          \
    ROTP_L(x8,x10, C.z,S.z); ROTP_H(x9,x11, C.z,S.z);                          \
    ROTP_L(x12,x14,C.w,S.w); ROTP_H(x13,x15,C.w,S.w);                          \
  } while (0)
#define HROTS4(C,S) do {                                                       \
    ROTP_L(x0,x4,  C.x,S.x); ROTP_H(x1,x5,  C.x,S.x);                          \
    ROTP_L(x2,x6,  C.y,S.y); ROTP_H(x3,x7,  C.y,S.y);                          \
    ROTP_L(x8,x12, C.z,S.z); ROTP_H(x9,x13, C.z,S.z);                          \
    ROTP_L(x10,x14,C.w,S.w); ROTP_H(x11,x15,C.w,S.w);                          \
  } while (0)
#define HROTS8(C,S) do {                                                       \
    ROTP_L(x0,x8,  C.x,S.x); ROTP_H(x1,x9,  C.x,S.x);                          \
    ROTP_L(x2,x10, C.y,S.y); ROTP_H(x3,x11, C.y,S.y);                          \
    ROTP_L(x4,x12, C.z,S.z); ROTP_H(x5,x13, C.z,S.z);                          \
    ROTP_L(x6,x14, C.w,S.w); ROTP_H(x7,x15, C.w,S.w);                          \
  } while (0)

#define HROT(P, K, M) M(P##c##K, P##s##K)

// activation in fp32 (values are h2 in registers; bias fp32 scalar per row)
#define ACTH(X, BF) do {                                                       \
    float _lo = (float)(X).x + (BF), _hi = (float)(X).y + (BF);                \
    _lo = 0.5f * (_lo + __builtin_amdgcn_sqrtf(_lo * _lo + 1.0f));             \
    _hi = 0.5f * (_hi + __builtin_amdgcn_sqrtf(_hi * _hi + 1.0f));             \
    X = __builtin_bit_cast(h2, PKU(_lo, _hi)); } while (0)

#define FENCE() __builtin_amdgcn_sched_barrier(0)

// process module M with set P; prefetch next module into set N (FULL=all 8
// layers, else IN 4 only). Barrier-free (each wave owns its private slab);
// fenced load blocks keep full-module prefetch distance (r10: +34% win).
#define PROC_MOD(P, N, CSN, ANN, ATN, INB, BIN, M, FULL) do {                  \
  const int a0=P##i0.x, a1=P##i0.y, a2=P##i0.z, a3=P##i0.w,                    \
            a4=P##i1.x, a5=P##i1.y, a6=P##i1.z, a7=P##i1.w,                    \
            a8=P##i2.x, a9=P##i2.y, a10=P##i2.z, a11=P##i2.w,                  \
            a12=P##i3.x, a13=P##i3.y, a14=P##i3.z, a15=P##i3.w;                \
  h2 x0=LDH(a0), x1=LDH(a1), x2=LDH(a2), x3=LDH(a3),                           \
     x4=LDH(a4), x5=LDH(a5), x6=LDH(a6), x7=LDH(a7),                           \
     x8=LDH(a8), x9=LDH(a9), x10=LDH(a10), x11=LDH(a11),                       \
     x12=LDH(a12), x13=LDH(a13), x14=LDH(a14), x15=LDH(a15);                   \
  if (FULL) { LOADCS8(N, CSN, ANN); } else { LOADCS4(N, CSN, ANN); }           \
  FENCE();                                                                     \
  HROT(P,0,HROTS1); HROT(P,1,HROTS2); HROT(P,2,HROTS4); HROT(P,3,HROTS8);      \
  ACTH(x0,P##bA.x); ACTH(x1,P##bA.y); ACTH(x2,P##bA.z); ACTH(x3,P##bA.w);      \
  ACTH(x4,P##bB.x); ACTH(x5,P##bB.y); ACTH(x6,P##bB.z); ACTH(x7,P##bB.w);      \
  const int _ab = ADDR(N_INW + (M)*N_GROW + (blk << 3));                       \
  STH(_ab+ 0,x0); STH(_ab+ 4,x1); STH(_ab+ 8,x2); STH(_ab+12,x3);              \
  STH(_ab+16,x4); STH(_ab+20,x5); STH(_ab+24,x6); STH(_ab+28,x7);              \
  LOAD_AB(N, ATN, INB, BIN);                                                   \
  FENCE();                                                                     \
  HROT(P,4,HROTS1); HROT(P,5,HROTS2); HROT(P,6,HROTS4); HROT(P,7,HROTS8);      \
  STH(a0,x0);  STH(a1,x1);  STH(a2,x2);  STH(a3,x3);                           \
  STH(a4,x4);  STH(a5,x5);  STH(a6,x6);  STH(a7,x7);                           \
  STH(a8,x8);  STH(a9,x9);  STH(a10,x10); STH(a11,x11);                        \
  STH(a12,x12); STH(a13,x13); STH(a14,x14); STH(a15,x15);                      \
} while (0)

template <bool USE_TABLE>
__global__ __launch_bounds__(N_THREADS, 2)   // <=256 VGPR
void butterfly_fused_kernel(const float* __restrict__ input,
                            const float* __restrict__ scales,
                            const float* __restrict__ biases,
                            const int*   __restrict__ indices,
                            const char*  __restrict__ cs_tab,
                            const int*   __restrict__ addr_tab,
                            const float* __restrict__ angles,
                            float* __restrict__ out) {
    extern __shared__ float ldsbuf[];
    const int t   = threadIdx.x;
    const int blk = t & 63;          // butterfly block = lane
    const int cp  = t >> 6;          // wave id; waves fully independent
    char* L = (char*)ldsbuf + cp * SLAB_B;   // private per-wave slab
    const int b   = blockIdx.x;
    // XCD swizzle: blockIdx%8 == x owns columns [x*512,(x+1)*512)
    const int cg  = ((((b & 7) * 128) + (b >> 3)) << 2) + (cp << 1);

    DECL_SET(A) DECL_SET(B)

    // prologue: module 0 params into A
    LOADCS8(A, cs_tab, angles);
    LOAD_AB(A, addr_tab, indices, biases);

    // init: rows 0..1023 = scales[r] * input[r][cg..cg+1] (fp16 pack)
#pragma unroll
    for (int k = 0; k < 16; ++k) {
        const int r = (k << 6) + blk;
        F2 v = *(const F2*)(input + (size_t)r * N_BATCH + cg);
        STH(ADDR(r), __builtin_bit_cast(h2, PKU(scales[r] * v.x, scales[r] * v.y)));
    }

    // next-module bases (module 1)
    const char*  csn = cs_tab + 16384;
    const float* ann = angles + 4096;
    const int*   atn = addr_tab + N_INW;
    const int*   inb = indices + N_INW;
    const float* bin = biases + N_GROW;

#pragma unroll 1
    for (int tt = 0; tt < 3; ++tt) {
        const int m = 2 * tt;
        PROC_MOD(A, B, csn, ann, atn, inb, bin, m, 1);
        csn += 16384; ann += 4096; atn += N_INW; inb += N_INW; bin += N_GROW;
        PROC_MOD(B, A, csn, ann, atn, inb, bin, m + 1, 1);
        csn += 16384; ann += 4096; atn += N_INW; inb += N_INW; bin += N_GROW;
    }
    // module 6 (A), prefetching module 7's IN layers into B
    PROC_MOD(A, B, csn, ann, atn, inb, bin, 6, 0);

    // epilogue: module 7 (B) — OUT rotations + scatter are dead code;
    // output = module-7 activations (convert fp16 -> fp32).
    {
        h2 x0=LDH(Bi0.x), x1=LDH(Bi0.y), x2=LDH(Bi0.z), x3=LDH(Bi0.w),
           x4=LDH(Bi1.x), x5=LDH(Bi1.y), x6=LDH(Bi1.z), x7=LDH(Bi1.w),
           x8=LDH(Bi2.x), x9=LDH(Bi2.y), x10=LDH(Bi2.z), x11=LDH(Bi2.w),
           x12=LDH(Bi3.x), x13=LDH(Bi3.y), x14=LDH(Bi3.z), x15=LDH(Bi3.w);
        FENCE();
        HROT(B,0,HROTS1); HROT(B,1,HROTS2); HROT(B,2,HROTS4); HROT(B,3,HROTS8);
        ACTH(x0,BbA.x); ACTH(x1,BbA.y); ACTH(x2,BbA.z); ACTH(x3,BbA.w);
        ACTH(x4,BbB.x); ACTH(x5,BbB.y); ACTH(x6,BbB.z); ACTH(x7,BbB.w);
#define OUTW(J, X) do { F2 _o; _o.x = (float)(X).x; _o.y = (float)(X).y;       \
        *(F2*)(out + (size_t)((blk<<3)+(J))*N_BATCH + cg) = _o; } while (0)
        OUTW(0,x0); OUTW(1,x1); OUTW(2,x2); OUTW(3,x3);
        OUTW(4,x4); OUTW(5,x5); OUTW(6,x6); OUTW(7,x7);
#undef OUTW
    }
}

// ---------------- host ----------------
extern "C" void kernel_launch(void* const* d_in, const int* in_sizes, int n_in,
                              void* d_out, int out_size, void* d_ws, size_t ws_size,
                              hipStream_t stream) {
    const float* input   = (const float*)d_in[0];
    const float* scales  = (const float*)d_in[1];
    const float* angles  = (const float*)d_in[2];
    const float* biases  = (const float*)d_in[3];
    const int*   indices = (const int*)d_in[4];
    float* out = (float*)d_out;

    const size_t cs_bytes  = (size_t)N_LAYERS * 2048;                    // 128 KB fp16
    const size_t adr_bytes = (size_t)N_DEPTH * N_INW * sizeof(int);      // 32 KB
    const size_t lds_bytes = (size_t)2 * SLAB_B;                         // 39168 B
    const int grid = N_BATCH / 4;                                        // 1024 WGs

    if (ws_size >= cs_bytes + adr_bytes) {
        _Float16* csh = (_Float16*)d_ws;
        int* addrs = (int*)((char*)d_ws + cs_bytes);
        precompute_kernel<<<(N_LAYERS * 512 + 255) / 256, 256, 0, stream>>>(
            angles, indices, csh, addrs);
        butterfly_fused_kernel<true><<<grid, N_THREADS, lds_bytes, stream>>>(
            input, scales, biases, indices, (const char*)csh, addrs, angles, out);
    } else {
        butterfly_fused_kernel<false><<<grid, N_THREADS, lds_bytes, stream>>>(
            input, scales, biases, indices, nullptr, nullptr, angles, out);
    }
}